// Round 6
// baseline (724.565 us; speedup 1.0000x reference)
//
#include <hip/hip_runtime.h>
#include <cstdint>
#include <cstddef>

// ---------------- types ----------------
typedef short short4v __attribute__((ext_vector_type(4)));
typedef short short8v __attribute__((ext_vector_type(8)));
typedef float f32x4   __attribute__((ext_vector_type(4)));

#define T_LEN  2048
#define HDIM   4096
#define NHEADS 32
#define HEADD  128
#define QKVN   4608   // (32 + 2*2) * 128

static __device__ __forceinline__ short f2bf(float f) {
  __bf16 h = (__bf16)f;               // RNE fptrunc
  return __builtin_bit_cast(short, h);
}

static __device__ __forceinline__ void gload_lds16(const void* g, void* l) {
  // async global->LDS, 16B per lane; LDS dest is wave-uniform base + lane*16
  __builtin_amdgcn_global_load_lds((const __attribute__((address_space(1))) void*)g,
                                   (__attribute__((address_space(3))) void*)l,
                                   16, 0, 0);
}

// ---------------- cast f32 -> bf16 (vectorized, G13) ----------------
__global__ void cast_f32_to_bf16(const float* __restrict__ in, short* __restrict__ out, int n4) {
  int idx = blockIdx.x * blockDim.x + threadIdx.x;
  int stride = gridDim.x * blockDim.x;
  const float4* in4 = (const float4*)in;
  short4v* out4 = (short4v*)out;
  for (int i = idx; i < n4; i += stride) {
    float4 v = in4[i];
    short4v o;
    o[0] = f2bf(v.x); o[1] = f2bf(v.y); o[2] = f2bf(v.z); o[3] = f2bf(v.w);
    out4[i] = o;
  }
}

// ---------------- GEMM  C[M][N] = A[M][K] * B[N][K]^T (+bias), f32 out ------
// A,B bf16. 128x128 tile, BK=32, 4 waves (2x2), wave = 64x64 via 4x4
// 16x16x32 MFMA frags. m97 structure: global_load_lds(16B) + 2 barriers/K-step.
__global__ __launch_bounds__(256, 2) void gemm_bt(
    const short* __restrict__ A,     // [M][K] bf16
    const short* __restrict__ B,     // [N][K] bf16
    const float* __restrict__ bias,  // [N] f32 or nullptr
    float* __restrict__ Cout,        // [M][N] f32
    int M, int N, int K)
{
  __shared__ short sA[128 * 32];
  __shared__ short sB[128 * 32];
  const int tid  = threadIdx.x;
  const int lane = tid & 63;
  const int wv   = tid >> 6;
  const int wr   = wv >> 1;
  const int wc   = wv & 1;
  const int bn0  = blockIdx.x * 128;
  const int bm0  = blockIdx.y * 128;

  // staging: thread t -> row=t>>2, kchunk=(t&3)*8 (16B each)
  const int row0 = tid >> 2;
  const int kc0  = (tid & 3) * 8;
  const int row1 = row0 + 64;
  short* lA0 = sA + wv * 64 * 8;           // wave-uniform LDS bases (lane*16B implicit)
  short* lA1 = sA + (256 + wv * 64) * 8;
  short* lB0 = sB + wv * 64 * 8;
  short* lB1 = sB + (256 + wv * 64) * 8;
  const short* gA0 = A + (size_t)(bm0 + row0) * K + kc0;
  const short* gA1 = A + (size_t)(bm0 + row1) * K + kc0;
  const short* gB0 = B + (size_t)(bn0 + row0) * K + kc0;
  const short* gB1 = B + (size_t)(bn0 + row1) * K + kc0;

  const int fr = lane & 15;         // fragment row/col
  const int fk = (lane >> 4) * 8;   // fragment k offset

  f32x4 zero = {0.f, 0.f, 0.f, 0.f};
  f32x4 acc[4][4];
#pragma unroll
  for (int m = 0; m < 4; m++)
#pragma unroll
    for (int n = 0; n < 4; n++) acc[m][n] = zero;

  for (int kt = 0; kt < K; kt += 32) {
    gload_lds16(gA0 + kt, lA0);
    gload_lds16(gA1 + kt, lA1);
    gload_lds16(gB0 + kt, lB0);
    gload_lds16(gB1 + kt, lB1);
    __syncthreads();   // drains vmcnt -> LDS ready
    short8v af[4], bfr[4];
#pragma unroll
    for (int m = 0; m < 4; m++)
      af[m] = *(const short8v*)(sA + (wr * 64 + m * 16 + fr) * 32 + fk);
#pragma unroll
    for (int n = 0; n < 4; n++)
      bfr[n] = *(const short8v*)(sB + (wc * 64 + n * 16 + fr) * 32 + fk);
#pragma unroll
    for (int m = 0; m < 4; m++)
#pragma unroll
      for (int n = 0; n < 4; n++)
        acc[m][n] = __builtin_amdgcn_mfma_f32_16x16x32_bf16(af[m], bfr[n], acc[m][n], 0, 0, 0);
    __syncthreads();   // before overwriting LDS
  }

  // epilogue: C/D layout col=lane&15, row=(lane>>4)*4+j  [m89 verified]
  const int rg = (lane >> 4) * 4;
#pragma unroll
  for (int m = 0; m < 4; m++) {
#pragma unroll
    for (int n = 0; n < 4; n++) {
      const int gcol = bn0 + wc * 64 + n * 16 + fr;
      const float bv = bias ? bias[gcol] : 0.0f;
#pragma unroll
      for (int j = 0; j < 4; j++) {
        const int grow = bm0 + wr * 64 + m * 16 + rg + j;
        Cout[(size_t)grow * N + gcol] = acc[m][n][j] + bv;
      }
    }
  }
}

// ---------------- per-head RMSNorm + RoPE + layout shuffle ----------------
// grid (T, 36): h<32 -> Q head, 32..33 -> K head, 34..35 -> V head.
// 64 lanes; lane i owns dims (2i, 2i+1) so RoPE pairs are lane-local.
__global__ __launch_bounds__(64) void qkv_post_kernel(
    const float* __restrict__ qkvf,      // [T][4608] f32 (bias already added)
    const int*   __restrict__ positions,
    const float* __restrict__ q_ln,      // [128] f32
    const float* __restrict__ k_ln,      // [128] f32
    short* __restrict__ Qb,   // [NH][T][HD]
    short* __restrict__ Kb,   // [NKV][T][HD]
    short* __restrict__ Vt)   // [NKV][HD][T]  (transposed for PV B-frags)
{
  const int t = blockIdx.x;
  const int h = blockIdx.y;
  const int lane = threadIdx.x;
  const float2 x2 = ((const float2*)(qkvf + (size_t)t * QKVN + h * HEADD))[lane];
  float x = x2.x, y = x2.y;

  if (h >= 34) { // V: cast + transpose only
    const int hv = h - 34;
    short* dst = Vt + ((size_t)hv * HEADD + 2 * lane) * T_LEN + t;
    dst[0]     = f2bf(x);
    dst[T_LEN] = f2bf(y);
    return;
  }

  float ss = x * x + y * y;
#pragma unroll
  for (int d = 32; d > 0; d >>= 1) ss += __shfl_xor(ss, d);
  const float r = rsqrtf(ss * (1.0f / 128.0f) + 1e-5f);
  const float* lnw = (h < 32) ? q_ln : k_ln;
  x = x * r * lnw[2 * lane];
  y = y * r * lnw[2 * lane + 1];

  if (lane < 32) { // rotary pairs (2i,2i+1), i<32: ang = pos * 10000^(-i/32)
    const float pos = (float)positions[t];
    const float ang = pos * powf(10000.0f, -(float)lane * (1.0f / 32.0f));
    const float c = cosf(ang), s = sinf(ang);
    const float r1 = x * c - y * s;
    const float r2 = y * c + x * s;
    x = r1; y = r2;
  }

  short* dst = (h < 32) ? (Qb + ((size_t)h * T_LEN + t) * HEADD + 2 * lane)
                        : (Kb + ((size_t)(h - 32) * T_LEN + t) * HEADD + 2 * lane);
  dst[0] = f2bf(x);
  dst[1] = f2bf(y);
}

// ---------------- causal flash attention, GQA 16:1 ----------------
// grid (T/64, NH), 4 waves; wave owns 16 q-rows. KV-tile = 32.
__global__ __launch_bounds__(256, 2) void attn_kernel(
    const short* __restrict__ Qb,   // [NH][T][HD]
    const short* __restrict__ Kb,   // [NKV][T][HD]
    const short* __restrict__ Vt,   // [NKV][HD][T]
    short* __restrict__ attn_out)   // [T][NH*HD] bf16
{
  __shared__ short pbuf[4][16 * 40];  // per-wave P tile, padded stride 40 (80B)
  const int qt   = blockIdx.x;
  const int h    = blockIdx.y;
  const int hkv  = h >> 4;
  const int tid  = threadIdx.x;
  const int lane = tid & 63;
  const int wv   = tid >> 6;
  const int qrow0 = qt * 64 + wv * 16;
  const int fr = lane & 15;
  const int fk = (lane >> 4) * 8;
  const int rg = (lane >> 4) * 4;

  // Q fragments in registers (A-operand: row=lane&15, k=(lane>>4)*8)
  const short* Qrow = Qb + ((size_t)h * T_LEN + qrow0 + fr) * HEADD + fk;
  short8v qf[4];
#pragma unroll
  for (int d0 = 0; d0 < 4; d0++) qf[d0] = *(const short8v*)(Qrow + d0 * 32);

  float mrow[4] = {-1e30f, -1e30f, -1e30f, -1e30f};
  float lrow[4] = {0.f, 0.f, 0.f, 0.f};
  f32x4 zero = {0.f, 0.f, 0.f, 0.f};
  f32x4 o[8];
#pragma unroll
  for (int d = 0; d < 8; d++) o[d] = zero;

  const short* Kh = Kb + (size_t)hkv * T_LEN * HEADD;
  const short* Vh = Vt + (size_t)hkv * HEADD * T_LEN;
  short* pb = pbuf[wv];
  const float scale = 0.08838834764831845f; // 128^-0.5
  const int s_end = qt * 64 + 64;

  for (int s0 = 0; s0 < s_end; s0 += 32) {
    // ---- scores: Q (A) x K^T (B); K rows are K-contiguous -> direct 16B loads
    float scv[2][4];
#pragma unroll
    for (int sub = 0; sub < 2; sub++) {
      f32x4 a = zero;
      const short* Krow = Kh + (size_t)(s0 + sub * 16 + fr) * HEADD + fk;
#pragma unroll
      for (int d0 = 0; d0 < 4; d0++) {
        short8v kf = *(const short8v*)(Krow + d0 * 32);
        a = __builtin_amdgcn_mfma_f32_16x16x32_bf16(qf[d0], kf, a, 0, 0, 0);
      }
      const int colp = s0 + sub * 16 + fr;
#pragma unroll
      for (int j = 0; j < 4; j++) {
        float v = a[j] * scale;
        if (colp > qrow0 + rg + j) v = -1e30f;   // causal mask
        scv[sub][j] = v;
      }
    }
    // ---- online softmax (row = 16-lane group, reg j)
    float corr[4];
#pragma unroll
    for (int j = 0; j < 4; j++) {
      float mx = fmaxf(scv[0][j], scv[1][j]);
#pragma unroll
      for (int d = 1; d < 16; d <<= 1) mx = fmaxf(mx, __shfl_xor(mx, d));
      const float mn = fmaxf(mrow[j], mx);
      const float c  = __expf(mrow[j] - mn);
      mrow[j] = mn;
      const float p0 = __expf(scv[0][j] - mn);
      const float p1 = __expf(scv[1][j] - mn);
      float rs = p0 + p1;
#pragma unroll
      for (int d = 1; d < 16; d <<= 1) rs += __shfl_xor(rs, d);
      lrow[j] = lrow[j] * c + rs;
      corr[j] = c;
      // C-layout -> LDS (row = q-local, col = s-local)
      pb[(rg + j) * 40 + fr]      = f2bf(p0);
      pb[(rg + j) * 40 + 16 + fr] = f2bf(p1);
    }
    asm volatile("" ::: "memory");  // order LDS writes before A-frag read
    // ---- P A-frag (row=fr, k=fk..fk+7), then PV with transposed V
    short8v pf = *(const short8v*)(pb + fr * 40 + fk);
#pragma unroll
    for (int df = 0; df < 8; df++) {
#pragma unroll
      for (int j = 0; j < 4; j++) o[df][j] *= corr[j];
      short8v vfr = *(const short8v*)(Vh + (size_t)(df * 16 + fr) * T_LEN + s0 + fk);
      o[df] = __builtin_amdgcn_mfma_f32_16x16x32_bf16(pf, vfr, o[df], 0, 0, 0);
    }
    asm volatile("" ::: "memory");  // order PV reads before next tile's writes
  }

#pragma unroll
  for (int df = 0; df < 8; df++) {
#pragma unroll
    for (int j = 0; j < 4; j++) {
      const float v = o[df][j] / lrow[j];
      attn_out[(size_t)(qrow0 + rg + j) * HDIM + h * HEADD + df * 16 + fr] = f2bf(v);
    }
  }
}

// ---------------- launch ----------------
extern "C" void kernel_launch(void* const* d_in, const int* in_sizes, int n_in,
                              void* d_out, int out_size, void* d_ws, size_t ws_size,
                              hipStream_t stream) {
  (void)out_size; (void)ws_size;
  // size-based input remap (robust to any d_in permutation; sizes are unique)
  int ip = 0, ih = 1, iwq = 2, ib = 3, iwd = 4, il0 = 5, il1 = 6;
  if (n_in == 7) {
    int p = -1, hh = -1, wq = -1, b = -1, wd = -1, l0 = -1, l1 = -1, ok = 1;
    for (int i = 0; i < 7; i++) {
      switch (in_sizes[i]) {
        case 2048:     p  = i; break;
        case 8388608:  hh = i; break;
        case 18874368: wq = i; break;
        case 4608:     b  = i; break;
        case 16777216: wd = i; break;
        case 128:      if (l0 < 0) l0 = i; else l1 = i; break;
        default:       ok = 0; break;
      }
    }
    if (ok && p >= 0 && hh >= 0 && wq >= 0 && b >= 0 && wd >= 0 && l0 >= 0 && l1 >= 0) {
      ip = p; ih = hh; iwq = wq; ib = b; iwd = wd; il0 = l0; il1 = l1;
    }
  }

  const int*   positions = (const int*)d_in[ip];
  const float* hidden    = (const float*)d_in[ih];
  const float* w_qkv     = (const float*)d_in[iwq];
  const float* b_qkv     = (const float*)d_in[ib];
  const float* w_dense   = (const float*)d_in[iwd];
  const float* q_ln      = (const float*)d_in[il0];
  const float* k_ln      = (const float*)d_in[il1];

  char* ws = (char*)d_ws;
  // lifetime-aliased workspace (peak ~92.3 MB):
  short* Ahs   = (short*)(ws + 0);                   // 16.8 MB (dead after gemm1)
  short* Qb    = (short*)(ws + 0);                   // 16.8 MB (aliases Ahs)
  short* Wqkv  = (short*)(ws + (size_t)16777216);    // 37.7 MB (dead after gemm1)
  short* Kb    = (short*)(ws + (size_t)16777216);    // 1.0 MB  (aliases Wqkv)
  short* Vt    = (short*)(ws + (size_t)17825792);    // 1.0 MB  (aliases Wqkv)
  short* Wd    = (short*)(ws + (size_t)18874368);    // 33.5 MB (aliases Wqkv)
  float* qkvf  = (float*)(ws + (size_t)54525952);    // 37.7 MB f32 (dead after qkv_post)
  short* attnb = (short*)(ws + (size_t)54525952);    // 16.8 MB (aliases qkvf)

  cast_f32_to_bf16<<<dim3(1024), dim3(256), 0, stream>>>(hidden, Ahs, (T_LEN * HDIM) / 4);
  cast_f32_to_bf16<<<dim3(2048), dim3(256), 0, stream>>>(w_qkv, Wqkv, (QKVN * HDIM) / 4);
  gemm_bt<<<dim3(QKVN / 128, T_LEN / 128), dim3(256), 0, stream>>>(
      Ahs, Wqkv, b_qkv, qkvf, T_LEN, QKVN, HDIM);
  qkv_post_kernel<<<dim3(T_LEN, 36), dim3(64), 0, stream>>>(
      qkvf, positions, q_ln, k_ln, Qb, Kb, Vt);
  cast_f32_to_bf16<<<dim3(2048), dim3(256), 0, stream>>>(w_dense, Wd, (HDIM * HDIM) / 4);
  attn_kernel<<<dim3(T_LEN / 64, NHEADS), dim3(256), 0, stream>>>(Qb, Kb, Vt, attnb);
  gemm_bt<<<dim3(HDIM / 128, T_LEN / 128), dim3(256), 0, stream>>>(
      attnb, Wd, nullptr, (float*)d_out, T_LEN, HDIM, HDIM);
}

// Round 7
// 711.656 us; speedup vs baseline: 1.0181x; 1.0181x over previous
//
#include <hip/hip_runtime.h>
#include <cstdint>
#include <cstddef>

// ---------------- types ----------------
typedef short short4v __attribute__((ext_vector_type(4)));
typedef short short8v __attribute__((ext_vector_type(8)));
typedef float f32x4   __attribute__((ext_vector_type(4)));

#define T_LEN  2048
#define HDIM   4096
#define NHEADS 32
#define HEADD  128
#define QKVN   4608   // (32 + 2*2) * 128

static __device__ __forceinline__ short f2bf(float f) {
  __bf16 h = (__bf16)f;               // RNE fptrunc
  return __builtin_bit_cast(short, h);
}

static __device__ __forceinline__ void gload_lds16(const void* g, void* l) {
  // async global->LDS, 16B per lane; LDS dest is wave-uniform base + lane*16
  __builtin_amdgcn_global_load_lds((const __attribute__((address_space(1))) void*)g,
                                   (__attribute__((address_space(3))) void*)l,
                                   16, 0, 0);
}

// ---------------- cast f32 -> bf16 (vectorized, G13) ----------------
__global__ void cast_f32_to_bf16(const float* __restrict__ in, short* __restrict__ out, int n4) {
  int idx = blockIdx.x * blockDim.x + threadIdx.x;
  int stride = gridDim.x * blockDim.x;
  const float4* in4 = (const float4*)in;
  short4v* out4 = (short4v*)out;
  for (int i = idx; i < n4; i += stride) {
    float4 v = in4[i];
    short4v o;
    o[0] = f2bf(v.x); o[1] = f2bf(v.y); o[2] = f2bf(v.z); o[3] = f2bf(v.w);
    out4[i] = o;
  }
}

// ---------------- GEMM  C[M][N] = A[M][K] * B[N][K]^T (+bias), f32 out ------
// A,B bf16. 128x128 tile, BK=32, 4 waves (2x2), wave = 64x64 via 4x4
// 16x16x32 MFMA frags. m97 structure: global_load_lds(16B) + 2 barriers/K-step.
__global__ __launch_bounds__(256, 2) void gemm_bt(
    const short* __restrict__ A,     // [M][K] bf16
    const short* __restrict__ B,     // [N][K] bf16
    const float* __restrict__ bias,  // [N] f32 or nullptr
    float* __restrict__ Cout,        // [M][N] f32
    int M, int N, int K)
{
  __shared__ short sA[128 * 32];
  __shared__ short sB[128 * 32];
  const int tid  = threadIdx.x;
  const int lane = tid & 63;
  const int wv   = tid >> 6;
  const int wr   = wv >> 1;
  const int wc   = wv & 1;
  const int bn0  = blockIdx.x * 128;
  const int bm0  = blockIdx.y * 128;

  const int row0 = tid >> 2;
  const int kc0  = (tid & 3) * 8;
  const int row1 = row0 + 64;
  short* lA0 = sA + wv * 64 * 8;
  short* lA1 = sA + (256 + wv * 64) * 8;
  short* lB0 = sB + wv * 64 * 8;
  short* lB1 = sB + (256 + wv * 64) * 8;
  const short* gA0 = A + (size_t)(bm0 + row0) * K + kc0;
  const short* gA1 = A + (size_t)(bm0 + row1) * K + kc0;
  const short* gB0 = B + (size_t)(bn0 + row0) * K + kc0;
  const short* gB1 = B + (size_t)(bn0 + row1) * K + kc0;

  const int fr = lane & 15;
  const int fk = (lane >> 4) * 8;

  f32x4 zero = {0.f, 0.f, 0.f, 0.f};
  f32x4 acc[4][4];
#pragma unroll
  for (int m = 0; m < 4; m++)
#pragma unroll
    for (int n = 0; n < 4; n++) acc[m][n] = zero;

  for (int kt = 0; kt < K; kt += 32) {
    gload_lds16(gA0 + kt, lA0);
    gload_lds16(gA1 + kt, lA1);
    gload_lds16(gB0 + kt, lB0);
    gload_lds16(gB1 + kt, lB1);
    __syncthreads();
    short8v af[4], bfr[4];
#pragma unroll
    for (int m = 0; m < 4; m++)
      af[m] = *(const short8v*)(sA + (wr * 64 + m * 16 + fr) * 32 + fk);
#pragma unroll
    for (int n = 0; n < 4; n++)
      bfr[n] = *(const short8v*)(sB + (wc * 64 + n * 16 + fr) * 32 + fk);
#pragma unroll
    for (int m = 0; m < 4; m++)
#pragma unroll
      for (int n = 0; n < 4; n++)
        acc[m][n] = __builtin_amdgcn_mfma_f32_16x16x32_bf16(af[m], bfr[n], acc[m][n], 0, 0, 0);
    __syncthreads();
  }

  const int rg = (lane >> 4) * 4;
#pragma unroll
  for (int m = 0; m < 4; m++) {
#pragma unroll
    for (int n = 0; n < 4; n++) {
      const int gcol = bn0 + wc * 64 + n * 16 + fr;
      const float bv = bias ? bias[gcol] : 0.0f;
#pragma unroll
      for (int j = 0; j < 4; j++) {
        const int grow = bm0 + wr * 64 + m * 16 + rg + j;
        Cout[(size_t)grow * N + gcol] = acc[m][n][j] + bv;
      }
    }
  }
}

// ---------------- per-head RMSNorm + RoPE + layout shuffle ----------------
__global__ __launch_bounds__(64) void qkv_post_kernel(
    const float* __restrict__ qkvf,      // [T][4608] f32 (bias already added)
    const int*   __restrict__ positions,
    const float* __restrict__ q_ln,      // [128] f32
    const float* __restrict__ k_ln,      // [128] f32
    short* __restrict__ Qb,   // [NH][T][HD]
    short* __restrict__ Kb,   // [NKV][T][HD]
    short* __restrict__ Vt)   // [NKV][HD][T]
{
  const int t = blockIdx.x;
  const int h = blockIdx.y;
  const int lane = threadIdx.x;
  const float2 x2 = ((const float2*)(qkvf + (size_t)t * QKVN + h * HEADD))[lane];
  float x = x2.x, y = x2.y;

  if (h >= 34) { // V: cast + transpose only
    const int hv = h - 34;
    short* dst = Vt + ((size_t)hv * HEADD + 2 * lane) * T_LEN + t;
    dst[0]     = f2bf(x);
    dst[T_LEN] = f2bf(y);
    return;
  }

  float ss = x * x + y * y;
#pragma unroll
  for (int d = 32; d > 0; d >>= 1) ss += __shfl_xor(ss, d);
  const float r = rsqrtf(ss * (1.0f / 128.0f) + 1e-5f);
  const float* lnw = (h < 32) ? q_ln : k_ln;
  x = x * r * lnw[2 * lane];
  y = y * r * lnw[2 * lane + 1];

  if (lane < 32) { // rotary pairs (2i,2i+1), i<32: ang = pos * 10000^(-i/32)
    const float pos = (float)positions[t];
    const float ang = pos * powf(10000.0f, -(float)lane * (1.0f / 32.0f));
    const float c = cosf(ang), s = sinf(ang);
    const float r1 = x * c - y * s;
    const float r2 = y * c + x * s;
    x = r1; y = r2;
  }

  short* dst = (h < 32) ? (Qb + ((size_t)h * T_LEN + t) * HEADD + 2 * lane)
                        : (Kb + ((size_t)(h - 32) * T_LEN + t) * HEADD + 2 * lane);
  dst[0] = f2bf(x);
  dst[1] = f2bf(y);
}

// ---------------- causal flash attention, GQA 16:1 ----------------
// grid (64 qtiles longest-first, 32 h), 2 waves x 16 q-rows, KVBLK=64.
// Latency-optimized softmax: defer-max (THR=8) + per-lane deferred l;
// common-path iteration has NO cross-lane ops.
__global__ __launch_bounds__(128, 2) void attn_kernel(
    const short* __restrict__ Qb,   // [NH][T][HD]
    const short* __restrict__ Kb,   // [NKV][T][HD]
    const short* __restrict__ Vt,   // [NKV][HD][T]
    short* __restrict__ attn_out)   // [T][NH*HD] bf16
{
  __shared__ short pbuf[2][16 * 76];  // per-wave P tile, stride 76 (152 B)
  const int qt   = gridDim.x - 1 - blockIdx.x;   // longest blocks first
  const int h    = blockIdx.y;
  const int hkv  = h >> 4;
  const int tid  = threadIdx.x;
  const int lane = tid & 63;
  const int wv   = tid >> 6;
  const int qrow0 = qt * 32 + wv * 16;
  const int fr = lane & 15;
  const int fk = (lane >> 4) * 8;
  const int rg = (lane >> 4) * 4;

  // Q fragments in registers (A-operand: row=lane&15, k=(lane>>4)*8)
  const short* Qrow = Qb + ((size_t)h * T_LEN + qrow0 + fr) * HEADD + fk;
  short8v qf[4];
#pragma unroll
  for (int d0 = 0; d0 < 4; d0++) qf[d0] = *(const short8v*)(Qrow + d0 * 32);

  float mrow[4] = {-1e30f, -1e30f, -1e30f, -1e30f};
  float lrow[4] = {0.f, 0.f, 0.f, 0.f};   // per-lane partial denominator
  f32x4 zero = {0.f, 0.f, 0.f, 0.f};
  f32x4 o[8];
#pragma unroll
  for (int d = 0; d < 8; d++) o[d] = zero;

  const short* Kh = Kb + (size_t)hkv * T_LEN * HEADD;
  const short* Vh = Vt + (size_t)hkv * HEADD * T_LEN;
  short* pb = pbuf[wv];
  const float scale = 0.08838834764831845f; // 128^-0.5
  const int s_end = qt * 32 + 32;

  for (int s0 = 0; s0 < s_end; s0 += 64) {
    // ---- scores: 4 sub-tiles of 16 KV rows each (K rows are d-contiguous)
    float scv[4][4];
#pragma unroll
    for (int sub = 0; sub < 4; sub++) {
      f32x4 a = zero;
      const short* Krow = Kh + (size_t)(s0 + sub * 16 + fr) * HEADD + fk;
#pragma unroll
      for (int d0 = 0; d0 < 4; d0++) {
        short8v kf = *(const short8v*)(Krow + d0 * 32);
        a = __builtin_amdgcn_mfma_f32_16x16x32_bf16(qf[d0], kf, a, 0, 0, 0);
      }
      const int colp = s0 + sub * 16 + fr;
#pragma unroll
      for (int j = 0; j < 4; j++) {
        float v = a[j] * scale;
        if (colp > qrow0 + rg + j) v = -1e30f;   // causal mask
        scv[sub][j] = v;
      }
    }
    // ---- per-lane tile max; defer-max gate (THR=8, wave-uniform)
    float pmax[4];
#pragma unroll
    for (int j = 0; j < 4; j++)
      pmax[j] = fmaxf(fmaxf(scv[0][j], scv[1][j]), fmaxf(scv[2][j], scv[3][j]));
    const float growth = fmaxf(fmaxf(pmax[0] - mrow[0], pmax[1] - mrow[1]),
                               fmaxf(pmax[2] - mrow[2], pmax[3] - mrow[3]));
    if (!__all(growth <= 8.0f)) {
      // rare path: full row-max reduce + rescale (first iteration always here)
#pragma unroll
      for (int j = 0; j < 4; j++) {
        float mx = pmax[j];
#pragma unroll
        for (int d = 1; d < 16; d <<= 1) mx = fmaxf(mx, __shfl_xor(mx, d));
        const float mn = fmaxf(mrow[j], mx);
        const float c  = __expf(mrow[j] - mn);
        mrow[j] = mn;
        lrow[j] *= c;
#pragma unroll
        for (int df = 0; df < 8; df++) o[df][j] *= c;
      }
    }
    // ---- common path: exp + per-lane l accumulation + P -> LDS (no shuffles)
#pragma unroll
    for (int j = 0; j < 4; j++) {
      float ps = 0.f;
#pragma unroll
      for (int sub = 0; sub < 4; sub++) {
        const float p = __expf(scv[sub][j] - mrow[j]);
        ps += p;
        pb[(rg + j) * 76 + sub * 16 + fr] = f2bf(p);
      }
      lrow[j] += ps;
    }
    asm volatile("" ::: "memory");  // order LDS writes before A-frag read
    // ---- PV: P A-frags (k-slices 0:32, 32:64) x transposed-V B-frags
    short8v pf0 = *(const short8v*)(pb + fr * 76 + fk);
    short8v pf1 = *(const short8v*)(pb + fr * 76 + 32 + fk);
#pragma unroll
    for (int df = 0; df < 8; df++) {
      short8v vf0 = *(const short8v*)(Vh + (size_t)(df * 16 + fr) * T_LEN + s0 + fk);
      o[df] = __builtin_amdgcn_mfma_f32_16x16x32_bf16(pf0, vf0, o[df], 0, 0, 0);
      short8v vf1 = *(const short8v*)(Vh + (size_t)(df * 16 + fr) * T_LEN + s0 + 32 + fk);
      o[df] = __builtin_amdgcn_mfma_f32_16x16x32_bf16(pf1, vf1, o[df], 0, 0, 0);
    }
    asm volatile("" ::: "memory");  // order PV reads before next tile's writes
  }

  // ---- final: one cross-lane sum reduce for the denominator
#pragma unroll
  for (int j = 0; j < 4; j++) {
#pragma unroll
    for (int d = 1; d < 16; d <<= 1) lrow[j] += __shfl_xor(lrow[j], d);
  }
#pragma unroll
  for (int df = 0; df < 8; df++) {
#pragma unroll
    for (int j = 0; j < 4; j++) {
      const float v = o[df][j] / lrow[j];
      attn_out[(size_t)(qrow0 + rg + j) * HDIM + h * HEADD + df * 16 + fr] = f2bf(v);
    }
  }
}

// ---------------- launch ----------------
extern "C" void kernel_launch(void* const* d_in, const int* in_sizes, int n_in,
                              void* d_out, int out_size, void* d_ws, size_t ws_size,
                              hipStream_t stream) {
  (void)out_size; (void)ws_size;
  // size-based input remap (robust to any d_in permutation; sizes are unique)
  int ip = 0, ih = 1, iwq = 2, ib = 3, iwd = 4, il0 = 5, il1 = 6;
  if (n_in == 7) {
    int p = -1, hh = -1, wq = -1, b = -1, wd = -1, l0 = -1, l1 = -1, ok = 1;
    for (int i = 0; i < 7; i++) {
      switch (in_sizes[i]) {
        case 2048:     p  = i; break;
        case 8388608:  hh = i; break;
        case 18874368: wq = i; break;
        case 4608:     b  = i; break;
        case 16777216: wd = i; break;
        case 128:      if (l0 < 0) l0 = i; else l1 = i; break;
        default:       ok = 0; break;
      }
    }
    if (ok && p >= 0 && hh >= 0 && wq >= 0 && b >= 0 && wd >= 0 && l0 >= 0 && l1 >= 0) {
      ip = p; ih = hh; iwq = wq; ib = b; iwd = wd; il0 = l0; il1 = l1;
    }
  }

  const int*   positions = (const int*)d_in[ip];
  const float* hidden    = (const float*)d_in[ih];
  const float* w_qkv     = (const float*)d_in[iwq];
  const float* b_qkv     = (const float*)d_in[ib];
  const float* w_dense   = (const float*)d_in[iwd];
  const float* q_ln      = (const float*)d_in[il0];
  const float* k_ln      = (const float*)d_in[il1];

  char* ws = (char*)d_ws;
  // lifetime-aliased workspace (peak ~92.3 MB):
  short* Ahs   = (short*)(ws + 0);                   // 16.8 MB (dead after gemm1)
  short* Qb    = (short*)(ws + 0);                   // 16.8 MB (aliases Ahs)
  short* Wqkv  = (short*)(ws + (size_t)16777216);    // 37.7 MB (dead after gemm1)
  short* Kb    = (short*)(ws + (size_t)16777216);    // 1.0 MB  (aliases Wqkv)
  short* Vt    = (short*)(ws + (size_t)17825792);    // 1.0 MB  (aliases Wqkv)
  short* Wd    = (short*)(ws + (size_t)18874368);    // 33.5 MB (aliases Wqkv)
  float* qkvf  = (float*)(ws + (size_t)54525952);    // 37.7 MB f32 (dead after qkv_post)
  short* attnb = (short*)(ws + (size_t)54525952);    // 16.8 MB (aliases qkvf)

  cast_f32_to_bf16<<<dim3(1024), dim3(256), 0, stream>>>(hidden, Ahs, (T_LEN * HDIM) / 4);
  cast_f32_to_bf16<<<dim3(2048), dim3(256), 0, stream>>>(w_qkv, Wqkv, (QKVN * HDIM) / 4);
  gemm_bt<<<dim3(QKVN / 128, T_LEN / 128), dim3(256), 0, stream>>>(
      Ahs, Wqkv, b_qkv, qkvf, T_LEN, QKVN, HDIM);
  qkv_post_kernel<<<dim3(T_LEN, 36), dim3(64), 0, stream>>>(
      qkvf, positions, q_ln, k_ln, Qb, Kb, Vt);
  cast_f32_to_bf16<<<dim3(2048), dim3(256), 0, stream>>>(w_dense, Wd, (HDIM * HDIM) / 4);
  attn_kernel<<<dim3(64, NHEADS), dim3(128), 0, stream>>>(Qb, Kb, Vt, attnb);
  gemm_bt<<<dim3(HDIM / 128, T_LEN / 128), dim3(256), 0, stream>>>(
      attnb, Wd, nullptr, (float*)d_out, T_LEN, HDIM, HDIM);
}

// Round 8
// 396.768 us; speedup vs baseline: 1.8262x; 1.7936x over previous
//
#include <hip/hip_runtime.h>
#include <cstdint>
#include <cstddef>

// ---------------- types ----------------
typedef short short4v __attribute__((ext_vector_type(4)));
typedef short short8v __attribute__((ext_vector_type(8)));
typedef float f32x4   __attribute__((ext_vector_type(4)));

#define T_LEN  2048
#define HDIM   4096
#define NHEADS 32
#define HEADD  128
#define QKVN   4608   // (32 + 2*2) * 128

static __device__ __forceinline__ short f2bf(float f) {
  __bf16 h = (__bf16)f;               // RNE fptrunc
  return __builtin_bit_cast(short, h);
}

static __device__ __forceinline__ void gload_lds16(const void* g, void* l) {
  // async global->LDS, 16B per lane; LDS dest is wave-uniform base + lane*16
  __builtin_amdgcn_global_load_lds((const __attribute__((address_space(1))) void*)g,
                                   (__attribute__((address_space(3))) void*)l,
                                   16, 0, 0);
}

// ---------------- cast f32 -> bf16 (vectorized, G13) ----------------
__global__ void cast_f32_to_bf16(const float* __restrict__ in, short* __restrict__ out, int n4) {
  int idx = blockIdx.x * blockDim.x + threadIdx.x;
  int stride = gridDim.x * blockDim.x;
  const float4* in4 = (const float4*)in;
  short4v* out4 = (short4v*)out;
  for (int i = idx; i < n4; i += stride) {
    float4 v = in4[i];
    short4v o;
    o[0] = f2bf(v.x); o[1] = f2bf(v.y); o[2] = f2bf(v.z); o[3] = f2bf(v.w);
    out4[i] = o;
  }
}

// ---------------- GEMM  C[M][N] = A[M][K] * B[N][K]^T (+bias), f32 out ------
// A,B bf16. 128x128 tile, BK=32, 4 waves (2x2), m97 structure.
__global__ __launch_bounds__(256, 2) void gemm_bt(
    const short* __restrict__ A,     // [M][K] bf16
    const short* __restrict__ B,     // [N][K] bf16
    const float* __restrict__ bias,  // [N] f32 or nullptr
    float* __restrict__ Cout,        // [M][N] f32
    int M, int N, int K)
{
  __shared__ short sA[128 * 32];
  __shared__ short sB[128 * 32];
  const int tid  = threadIdx.x;
  const int lane = tid & 63;
  const int wv   = tid >> 6;
  const int wr   = wv >> 1;
  const int wc   = wv & 1;
  const int bn0  = blockIdx.x * 128;
  const int bm0  = blockIdx.y * 128;

  const int row0 = tid >> 2;
  const int kc0  = (tid & 3) * 8;
  const int row1 = row0 + 64;
  short* lA0 = sA + wv * 64 * 8;
  short* lA1 = sA + (256 + wv * 64) * 8;
  short* lB0 = sB + wv * 64 * 8;
  short* lB1 = sB + (256 + wv * 64) * 8;
  const short* gA0 = A + (size_t)(bm0 + row0) * K + kc0;
  const short* gA1 = A + (size_t)(bm0 + row1) * K + kc0;
  const short* gB0 = B + (size_t)(bn0 + row0) * K + kc0;
  const short* gB1 = B + (size_t)(bn0 + row1) * K + kc0;

  const int fr = lane & 15;
  const int fk = (lane >> 4) * 8;

  f32x4 zero = {0.f, 0.f, 0.f, 0.f};
  f32x4 acc[4][4];
#pragma unroll
  for (int m = 0; m < 4; m++)
#pragma unroll
    for (int n = 0; n < 4; n++) acc[m][n] = zero;

  for (int kt = 0; kt < K; kt += 32) {
    gload_lds16(gA0 + kt, lA0);
    gload_lds16(gA1 + kt, lA1);
    gload_lds16(gB0 + kt, lB0);
    gload_lds16(gB1 + kt, lB1);
    __syncthreads();
    short8v af[4], bfr[4];
#pragma unroll
    for (int m = 0; m < 4; m++)
      af[m] = *(const short8v*)(sA + (wr * 64 + m * 16 + fr) * 32 + fk);
#pragma unroll
    for (int n = 0; n < 4; n++)
      bfr[n] = *(const short8v*)(sB + (wc * 64 + n * 16 + fr) * 32 + fk);
#pragma unroll
    for (int m = 0; m < 4; m++)
#pragma unroll
      for (int n = 0; n < 4; n++)
        acc[m][n] = __builtin_amdgcn_mfma_f32_16x16x32_bf16(af[m], bfr[n], acc[m][n], 0, 0, 0);
    __syncthreads();
  }

  const int rg = (lane >> 4) * 4;
#pragma unroll
  for (int m = 0; m < 4; m++) {
#pragma unroll
    for (int n = 0; n < 4; n++) {
      const int gcol = bn0 + wc * 64 + n * 16 + fr;
      const float bv = bias ? bias[gcol] : 0.0f;
#pragma unroll
      for (int j = 0; j < 4; j++) {
        const int grow = bm0 + wr * 64 + m * 16 + rg + j;
        Cout[(size_t)grow * N + gcol] = acc[m][n][j] + bv;
      }
    }
  }
}

// ---------------- per-head RMSNorm + RoPE + layout shuffle ----------------
__global__ __launch_bounds__(64) void qkv_post_kernel(
    const float* __restrict__ qkvf,      // [T][4608] f32 (bias already added)
    const int*   __restrict__ positions,
    const float* __restrict__ q_ln,      // [128] f32
    const float* __restrict__ k_ln,      // [128] f32
    short* __restrict__ Qb,   // [NH][T][HD]
    short* __restrict__ Kb,   // [NKV][T][HD]
    short* __restrict__ Vt)   // [NKV][HD][T]
{
  const int t = blockIdx.x;
  const int h = blockIdx.y;
  const int lane = threadIdx.x;
  const float2 x2 = ((const float2*)(qkvf + (size_t)t * QKVN + h * HEADD))[lane];
  float x = x2.x, y = x2.y;

  if (h >= 34) { // V: cast + transpose only
    const int hv = h - 34;
    short* dst = Vt + ((size_t)hv * HEADD + 2 * lane) * T_LEN + t;
    dst[0]     = f2bf(x);
    dst[T_LEN] = f2bf(y);
    return;
  }

  float ss = x * x + y * y;
#pragma unroll
  for (int d = 32; d > 0; d >>= 1) ss += __shfl_xor(ss, d);
  const float r = rsqrtf(ss * (1.0f / 128.0f) + 1e-5f);
  const float* lnw = (h < 32) ? q_ln : k_ln;
  x = x * r * lnw[2 * lane];
  y = y * r * lnw[2 * lane + 1];

  if (lane < 32) { // rotary pairs (2i,2i+1), i<32: ang = pos * 10000^(-i/32)
    const float pos = (float)positions[t];
    const float ang = pos * powf(10000.0f, -(float)lane * (1.0f / 32.0f));
    const float c = cosf(ang), s = sinf(ang);
    const float r1 = x * c - y * s;
    const float r2 = y * c + x * s;
    x = r1; y = r2;
  }

  short* dst = (h < 32) ? (Qb + ((size_t)h * T_LEN + t) * HEADD + 2 * lane)
                        : (Kb + ((size_t)(h - 32) * T_LEN + t) * HEADD + 2 * lane);
  dst[0] = f2bf(x);
  dst[1] = f2bf(y);
}

// ---------------- causal flash attention, GQA 16:1 ----------------
// grid (32 row-tiles longest-first, 32 h), 4 waves x 16 q-rows = 64 rows/block.
// K/V tiles staged once per block-iter into XOR-swizzled LDS (T2, rule #21:
// linear gload_lds dest + inverse-swizzled global source + swizzled ds_read),
// double-buffered 2-phase (T3-minimum). Defer-max softmax (T13), per-lane l.
__global__ __launch_bounds__(256, 2) void attn_kernel(
    const short* __restrict__ Qb,   // [NH][T][HD]
    const short* __restrict__ Kb,   // [NKV][T][HD]
    const short* __restrict__ Vt,   // [NKV][HD][T]
    short* __restrict__ attn_out)   // [T][NH*HD] bf16
{
  __shared__ short Ks[2][64 * 128];   // [s][d], swizzled, 2x16KB
  __shared__ short Vs[2][128 * 64];   // [d][s], swizzled, 2x16KB
  __shared__ short pbuf[4][16 * 76];  // per-wave P tile, stride 76 (0-conflict)
  const int blk  = gridDim.x - 1 - blockIdx.x;   // longest blocks first
  const int h    = blockIdx.y;
  const int hkv  = h >> 4;
  const int tid  = threadIdx.x;
  const int lane = tid & 63;
  const int wv   = tid >> 6;
  const int B0   = blk * 64;
  const int qrow0 = B0 + wv * 16;
  const int fr = lane & 15;
  const int fk = (lane >> 4) * 8;     // shorts
  const int fkb = (lane >> 4) << 4;   // bytes
  const int rg = (lane >> 4) * 4;

  const short* Kh = Kb + (size_t)hkv * T_LEN * HEADD;
  const short* Vh = Vt + (size_t)hkv * HEADD * T_LEN;

  // Q fragments in registers (A-operand: row=lane&15, k=(lane>>4)*8)
  const short* Qrow = Qb + ((size_t)h * T_LEN + qrow0 + fr) * HEADD + fk;
  short8v qf[4];
#pragma unroll
  for (int d0 = 0; d0 < 4; d0++) qf[d0] = *(const short8v*)(Qrow + d0 * 32);

  float mrow[4] = {-1e30f, -1e30f, -1e30f, -1e30f};
  float lrow[4] = {0.f, 0.f, 0.f, 0.f};
  f32x4 zero = {0.f, 0.f, 0.f, 0.f};
  f32x4 o[8];
#pragma unroll
  for (int d = 0; d < 8; d++) o[d] = zero;

  short* pb = pbuf[wv];
  const float scale = 0.08838834764831845f; // 128^-0.5
  const int nt = blk + 1;                   // KV tiles of 64

  // stage tile t into buffer b: inverse-swizzled SOURCE, linear LDS dest
  auto STAGE = [&](int b, int t) {
    const int s0 = t * 64;
#pragma unroll
    for (int i = 0; i < 4; i++) {          // K: [row s 0..63][col d], 256B rows
      const int c    = i * 256 + tid;
      const int row  = c >> 4;
      const int colb = (c & 15) << 4;
      const int scol = (colb ^ ((row & 7) << 4)) >> 1;
      gload_lds16(Kh + (size_t)(s0 + row) * HEADD + scol,
                  (char*)&Ks[b][0] + (size_t)(i * 256 + wv * 64) * 16);
    }
#pragma unroll
    for (int i = 0; i < 4; i++) {          // V: [row d 0..127][col s], 128B rows
      const int c    = i * 256 + tid;
      const int row  = c >> 3;
      const int colb = (c & 7) << 4;
      const int scol = (colb ^ ((row & 7) << 4)) >> 1;
      gload_lds16(Vh + (size_t)row * T_LEN + s0 + scol,
                  (char*)&Vs[b][0] + (size_t)(i * 256 + wv * 64) * 16);
    }
  };

  int cur = 0;
  STAGE(0, 0);
  __syncthreads();   // implicit vmcnt(0) drain -> tile 0 ready

  for (int t = 0; t < nt; ++t) {
    if (t + 1 < nt) STAGE(cur ^ 1, t + 1);   // prefetch next tile (T3 2-phase)
    const int s0 = t * 64;
    const char* KsB = (const char*)&Ks[cur][0];
    const char* VsB = (const char*)&Vs[cur][0];

    // ---- scores: 4 sub-tiles of 16 KV rows (swizzled ds_read_b128)
    float scv[4][4];
#pragma unroll
    for (int sub = 0; sub < 4; sub++) {
      f32x4 a = zero;
      const int krow = sub * 16 + fr;
      const char* Kbase = KsB + krow * 256;
      const int swz = (fr & 7) << 4;
#pragma unroll
      for (int d0 = 0; d0 < 4; d0++) {
        short8v kf = *(const short8v*)(Kbase + ((d0 * 64 + fkb) ^ swz));
        a = __builtin_amdgcn_mfma_f32_16x16x32_bf16(qf[d0], kf, a, 0, 0, 0);
      }
      const int colp = s0 + sub * 16 + fr;
#pragma unroll
      for (int j = 0; j < 4; j++) {
        float v = a[j] * scale;
        if (colp > qrow0 + rg + j) v = -1e30f;   // causal mask
        scv[sub][j] = v;
      }
    }
    // ---- defer-max gate (T13, THR=8)
    float pmax[4];
#pragma unroll
    for (int j = 0; j < 4; j++)
      pmax[j] = fmaxf(fmaxf(scv[0][j], scv[1][j]), fmaxf(scv[2][j], scv[3][j]));
    const float growth = fmaxf(fmaxf(pmax[0] - mrow[0], pmax[1] - mrow[1]),
                               fmaxf(pmax[2] - mrow[2], pmax[3] - mrow[3]));
    if (!__all(growth <= 8.0f)) {
#pragma unroll
      for (int j = 0; j < 4; j++) {
        float mx = pmax[j];
#pragma unroll
        for (int d = 1; d < 16; d <<= 1) mx = fmaxf(mx, __shfl_xor(mx, d));
        const float mn = fmaxf(mrow[j], mx);
        const float c  = __expf(mrow[j] - mn);
        mrow[j] = mn;
        lrow[j] *= c;
#pragma unroll
        for (int df = 0; df < 8; df++) o[df][j] *= c;
      }
    }
    // ---- exp + per-lane l + P -> LDS (no cross-lane ops)
#pragma unroll
    for (int j = 0; j < 4; j++) {
      float ps = 0.f;
#pragma unroll
      for (int sub = 0; sub < 4; sub++) {
        const float p = __expf(scv[sub][j] - mrow[j]);
        ps += p;
        pb[(rg + j) * 76 + sub * 16 + fr] = f2bf(p);
      }
      lrow[j] += ps;
    }
    asm volatile("" ::: "memory");
    // ---- PV: P A-frags x swizzled V B-frags
    short8v pf0 = *(const short8v*)(pb + fr * 76 + fk);
    short8v pf1 = *(const short8v*)(pb + fr * 76 + 32 + fk);
#pragma unroll
    for (int df = 0; df < 8; df++) {
      const int vrow = df * 16 + fr;
      const char* Vbase = VsB + vrow * 128;
      const int swz = (fr & 7) << 4;
      short8v vf0 = *(const short8v*)(Vbase + ((0 + fkb) ^ swz));
      o[df] = __builtin_amdgcn_mfma_f32_16x16x32_bf16(pf0, vf0, o[df], 0, 0, 0);
      short8v vf1 = *(const short8v*)(Vbase + ((64 + fkb) ^ swz));
      o[df] = __builtin_amdgcn_mfma_f32_16x16x32_bf16(pf1, vf1, o[df], 0, 0, 0);
    }
    __syncthreads();   // drains vmcnt (prefetch landed) + frees buffer cur
    cur ^= 1;
  }

  // ---- final denominator reduce + output
#pragma unroll
  for (int j = 0; j < 4; j++) {
#pragma unroll
    for (int d = 1; d < 16; d <<= 1) lrow[j] += __shfl_xor(lrow[j], d);
  }
#pragma unroll
  for (int df = 0; df < 8; df++) {
#pragma unroll
    for (int j = 0; j < 4; j++) {
      const float v = o[df][j] / lrow[j];
      attn_out[(size_t)(qrow0 + rg + j) * HDIM + h * HEADD + df * 16 + fr] = f2bf(v);
    }
  }
}

// ---------------- launch ----------------
extern "C" void kernel_launch(void* const* d_in, const int* in_sizes, int n_in,
                              void* d_out, int out_size, void* d_ws, size_t ws_size,
                              hipStream_t stream) {
  (void)out_size; (void)ws_size;
  // size-based input remap (robust to any d_in permutation; sizes are unique)
  int ip = 0, ih = 1, iwq = 2, ib = 3, iwd = 4, il0 = 5, il1 = 6;
  if (n_in == 7) {
    int p = -1, hh = -1, wq = -1, b = -1, wd = -1, l0 = -1, l1 = -1, ok = 1;
    for (int i = 0; i < 7; i++) {
      switch (in_sizes[i]) {
        case 2048:     p  = i; break;
        case 8388608:  hh = i; break;
        case 18874368: wq = i; break;
        case 4608:     b  = i; break;
        case 16777216: wd = i; break;
        case 128:      if (l0 < 0) l0 = i; else l1 = i; break;
        default:       ok = 0; break;
      }
    }
    if (ok && p >= 0 && hh >= 0 && wq >= 0 && b >= 0 && wd >= 0 && l0 >= 0 && l1 >= 0) {
      ip = p; ih = hh; iwq = wq; ib = b; iwd = wd; il0 = l0; il1 = l1;
    }
  }

  const int*   positions = (const int*)d_in[ip];
  const float* hidden    = (const float*)d_in[ih];
  const float* w_qkv     = (const float*)d_in[iwq];
  const float* b_qkv     = (const float*)d_in[ib];
  const float* w_dense   = (const float*)d_in[iwd];
  const float* q_ln      = (const float*)d_in[il0];
  const float* k_ln      = (const float*)d_in[il1];

  char* ws = (char*)d_ws;
  // lifetime-aliased workspace (peak ~92.3 MB):
  short* Ahs   = (short*)(ws + 0);                   // 16.8 MB (dead after gemm1)
  short* Qb    = (short*)(ws + 0);                   // 16.8 MB (aliases Ahs)
  short* Wqkv  = (short*)(ws + (size_t)16777216);    // 37.7 MB (dead after gemm1)
  short* Kb    = (short*)(ws + (size_t)16777216);    // 1.0 MB  (aliases Wqkv)
  short* Vt    = (short*)(ws + (size_t)17825792);    // 1.0 MB  (aliases Wqkv)
  short* Wd    = (short*)(ws + (size_t)18874368);    // 33.5 MB (aliases Wqkv)
  float* qkvf  = (float*)(ws + (size_t)54525952);    // 37.7 MB f32 (dead after qkv_post)
  short* attnb = (short*)(ws + (size_t)54525952);    // 16.8 MB (aliases qkvf)

  cast_f32_to_bf16<<<dim3(1024), dim3(256), 0, stream>>>(hidden, Ahs, (T_LEN * HDIM) / 4);
  cast_f32_to_bf16<<<dim3(2048), dim3(256), 0, stream>>>(w_qkv, Wqkv, (QKVN * HDIM) / 4);
  gemm_bt<<<dim3(QKVN / 128, T_LEN / 128), dim3(256), 0, stream>>>(
      Ahs, Wqkv, b_qkv, qkvf, T_LEN, QKVN, HDIM);
  qkv_post_kernel<<<dim3(T_LEN, 36), dim3(64), 0, stream>>>(
      qkvf, positions, q_ln, k_ln, Qb, Kb, Vt);
  cast_f32_to_bf16<<<dim3(2048), dim3(256), 0, stream>>>(w_dense, Wd, (HDIM * HDIM) / 4);
  attn_kernel<<<dim3(32, NHEADS), dim3(256), 0, stream>>>(Qb, Kb, Vt, attnb);
  gemm_bt<<<dim3(HDIM / 128, T_LEN / 128), dim3(256), 0, stream>>>(
      attnb, Wd, nullptr, (float*)d_out, T_LEN, HDIM, HDIM);
}

// Round 9
// 353.205 us; speedup vs baseline: 2.0514x; 1.1233x over previous
//
#include <hip/hip_runtime.h>
#include <cstdint>
#include <cstddef>

// ---------------- types ----------------
typedef short short4v __attribute__((ext_vector_type(4)));
typedef short short8v __attribute__((ext_vector_type(8)));
typedef float f32x4   __attribute__((ext_vector_type(4)));

#define T_LEN  2048
#define HDIM   4096
#define NHEADS 32
#define HEADD  128
#define QKVN   4608   // (32 + 2*2) * 128

static __device__ __forceinline__ short f2bf(float f) {
  __bf16 h = (__bf16)f;               // RNE fptrunc
  return __builtin_bit_cast(short, h);
}

static __device__ __forceinline__ void gload_lds16(const void* g, void* l) {
  // async global->LDS, 16B per lane; LDS dest is wave-uniform base + lane*16
  __builtin_amdgcn_global_load_lds((const __attribute__((address_space(1))) void*)g,
                                   (__attribute__((address_space(3))) void*)l,
                                   16, 0, 0);
}

// ---------------- cast f32 -> bf16 (vectorized, G13) ----------------
__global__ void cast_f32_to_bf16(const float* __restrict__ in, short* __restrict__ out, int n4) {
  int idx = blockIdx.x * blockDim.x + threadIdx.x;
  int stride = gridDim.x * blockDim.x;
  const float4* in4 = (const float4*)in;
  short4v* out4 = (short4v*)out;
  for (int i = idx; i < n4; i += stride) {
    float4 v = in4[i];
    short4v o;
    o[0] = f2bf(v.x); o[1] = f2bf(v.y); o[2] = f2bf(v.z); o[3] = f2bf(v.w);
    out4[i] = o;
  }
}

// ---------------- GEMM  C[M][N] = A[M][K] * B[N][K]^T (+bias), f32 out ------
// A,B bf16. 128x128 tile, BK=32, 4 waves (2x2), m97 structure.
__global__ __launch_bounds__(256, 2) void gemm_bt(
    const short* __restrict__ A,     // [M][K] bf16
    const short* __restrict__ B,     // [N][K] bf16
    const float* __restrict__ bias,  // [N] f32 or nullptr
    float* __restrict__ Cout,        // [M][N] f32
    int M, int N, int K)
{
  __shared__ short sA[128 * 32];
  __shared__ short sB[128 * 32];
  const int tid  = threadIdx.x;
  const int lane = tid & 63;
  const int wv   = tid >> 6;
  const int wr   = wv >> 1;
  const int wc   = wv & 1;
  const int bn0  = blockIdx.x * 128;
  const int bm0  = blockIdx.y * 128;

  const int row0 = tid >> 2;
  const int kc0  = (tid & 3) * 8;
  const int row1 = row0 + 64;
  short* lA0 = sA + wv * 64 * 8;
  short* lA1 = sA + (256 + wv * 64) * 8;
  short* lB0 = sB + wv * 64 * 8;
  short* lB1 = sB + (256 + wv * 64) * 8;
  const short* gA0 = A + (size_t)(bm0 + row0) * K + kc0;
  const short* gA1 = A + (size_t)(bm0 + row1) * K + kc0;
  const short* gB0 = B + (size_t)(bn0 + row0) * K + kc0;
  const short* gB1 = B + (size_t)(bn0 + row1) * K + kc0;

  const int fr = lane & 15;
  const int fk = (lane >> 4) * 8;

  f32x4 zero = {0.f, 0.f, 0.f, 0.f};
  f32x4 acc[4][4];
#pragma unroll
  for (int m = 0; m < 4; m++)
#pragma unroll
    for (int n = 0; n < 4; n++) acc[m][n] = zero;

  for (int kt = 0; kt < K; kt += 32) {
    gload_lds16(gA0 + kt, lA0);
    gload_lds16(gA1 + kt, lA1);
    gload_lds16(gB0 + kt, lB0);
    gload_lds16(gB1 + kt, lB1);
    __syncthreads();
    short8v af[4], bfr[4];
#pragma unroll
    for (int m = 0; m < 4; m++)
      af[m] = *(const short8v*)(sA + (wr * 64 + m * 16 + fr) * 32 + fk);
#pragma unroll
    for (int n = 0; n < 4; n++)
      bfr[n] = *(const short8v*)(sB + (wc * 64 + n * 16 + fr) * 32 + fk);
#pragma unroll
    for (int m = 0; m < 4; m++)
#pragma unroll
      for (int n = 0; n < 4; n++)
        acc[m][n] = __builtin_amdgcn_mfma_f32_16x16x32_bf16(af[m], bfr[n], acc[m][n], 0, 0, 0);
    __syncthreads();
  }

  const int rg = (lane >> 4) * 4;
#pragma unroll
  for (int m = 0; m < 4; m++) {
#pragma unroll
    for (int n = 0; n < 4; n++) {
      const int gcol = bn0 + wc * 64 + n * 16 + fr;
      const float bv = bias ? bias[gcol] : 0.0f;
#pragma unroll
      for (int j = 0; j < 4; j++) {
        const int grow = bm0 + wr * 64 + m * 16 + rg + j;
        Cout[(size_t)grow * N + gcol] = acc[m][n][j] + bv;
      }
    }
  }
}

// ---------------- per-head RMSNorm + RoPE + layout shuffle ----------------
__global__ __launch_bounds__(64) void qkv_post_kernel(
    const float* __restrict__ qkvf,      // [T][4608] f32 (bias already added)
    const int*   __restrict__ positions,
    const float* __restrict__ q_ln,      // [128] f32
    const float* __restrict__ k_ln,      // [128] f32
    short* __restrict__ Qb,   // [NH][T][HD]
    short* __restrict__ Kb,   // [NKV][T][HD]
    short* __restrict__ Vt)   // [NKV][HD][T]
{
  const int t = blockIdx.x;
  const int h = blockIdx.y;
  const int lane = threadIdx.x;
  const float2 x2 = ((const float2*)(qkvf + (size_t)t * QKVN + h * HEADD))[lane];
  float x = x2.x, y = x2.y;

  if (h >= 34) { // V: cast + transpose only
    const int hv = h - 34;
    short* dst = Vt + ((size_t)hv * HEADD + 2 * lane) * T_LEN + t;
    dst[0]     = f2bf(x);
    dst[T_LEN] = f2bf(y);
    return;
  }

  float ss = x * x + y * y;
#pragma unroll
  for (int d = 32; d > 0; d >>= 1) ss += __shfl_xor(ss, d);
  const float r = rsqrtf(ss * (1.0f / 128.0f) + 1e-5f);
  const float* lnw = (h < 32) ? q_ln : k_ln;
  x = x * r * lnw[2 * lane];
  y = y * r * lnw[2 * lane + 1];

  if (lane < 32) { // rotary pairs (2i,2i+1), i<32: ang = pos * 10000^(-i/32)
    const float pos = (float)positions[t];
    const float ang = pos * powf(10000.0f, -(float)lane * (1.0f / 32.0f));
    const float c = cosf(ang), s = sinf(ang);
    const float r1 = x * c - y * s;
    const float r2 = y * c + x * s;
    x = r1; y = r2;
  }

  short* dst = (h < 32) ? (Qb + ((size_t)h * T_LEN + t) * HEADD + 2 * lane)
                        : (Kb + ((size_t)(h - 32) * T_LEN + t) * HEADD + 2 * lane);
  dst[0] = f2bf(x);
  dst[1] = f2bf(y);
}

// ---------------- causal flash attention, GQA 16:1 ----------------
// grid (16 row-tiles longest-first, 32 h), 4 waves x 32 q-rows = 128 rows/blk.
// K/V staged per block-iter into XOR-swizzled LDS (2-phase dbuf); each K/V
// fragment read feeds 2 MFMAs (two 16-row groups). Mask only last 2 tiles.
// Defer-max softmax (T13), per-lane deferred denominator.
__global__ __launch_bounds__(256, 2) void attn_kernel(
    const short* __restrict__ Qb,   // [NH][T][HD]
    const short* __restrict__ Kb,   // [NKV][T][HD]
    const short* __restrict__ Vt,   // [NKV][HD][T]
    short* __restrict__ attn_out)   // [T][NH*HD] bf16
{
  __shared__ short Ks[2][64 * 128];   // [s][d] swizzled, 2x16KB
  __shared__ short Vs[2][128 * 64];   // [d][s] swizzled, 2x16KB
  __shared__ short pbuf[4][32 * 64];  // per-wave P tile [row][col] swizzled, 16KB
  const int blk  = gridDim.x - 1 - blockIdx.x;   // longest blocks first
  const int h    = blockIdx.y;
  const int hkv  = h >> 4;
  const int tid  = threadIdx.x;
  const int lane = tid & 63;
  const int wv   = tid >> 6;
  const int B0   = blk * 128;
  const int qrow0 = B0 + wv * 32;
  const int fr = lane & 15;
  const int fk = (lane >> 4) * 8;     // shorts
  const int fkb = (lane >> 4) << 4;   // bytes
  const int rg = (lane >> 4) * 4;
  const int swz = (fr & 7) << 4;

  const short* Kh = Kb + (size_t)hkv * T_LEN * HEADD;
  const short* Vh = Vt + (size_t)hkv * HEADD * T_LEN;

  // Q fragments, two 16-row groups (A-operand: row=lane&15, k=(lane>>4)*8)
  short8v qf[2][4];
#pragma unroll
  for (int g = 0; g < 2; g++) {
    const short* Qrow = Qb + ((size_t)h * T_LEN + qrow0 + g * 16 + fr) * HEADD + fk;
#pragma unroll
    for (int d0 = 0; d0 < 4; d0++) qf[g][d0] = *(const short8v*)(Qrow + d0 * 32);
  }

  float mrow[2][4], lrow[2][4];
#pragma unroll
  for (int g = 0; g < 2; g++)
#pragma unroll
    for (int j = 0; j < 4; j++) { mrow[g][j] = -1e30f; lrow[g][j] = 0.f; }
  f32x4 zero = {0.f, 0.f, 0.f, 0.f};
  f32x4 o[2][8];
#pragma unroll
  for (int g = 0; g < 2; g++)
#pragma unroll
    for (int d = 0; d < 8; d++) o[g][d] = zero;

  char* pb = (char*)&pbuf[wv][0];
  const float scale = 0.08838834764831845f; // 128^-0.5
  const int nt = 2 * blk + 2;               // KV tiles of 64

  // stage tile t into buffer b: inverse-swizzled SOURCE, linear LDS dest
  auto STAGE = [&](int b, int t) {
    const int s0 = t * 64;
#pragma unroll
    for (int i = 0; i < 4; i++) {          // K: [row s 0..63][col d], 256B rows
      const int c    = i * 256 + tid;
      const int row  = c >> 4;
      const int colb = (c & 15) << 4;
      const int scol = (colb ^ ((row & 7) << 4)) >> 1;
      gload_lds16(Kh + (size_t)(s0 + row) * HEADD + scol,
                  (char*)&Ks[b][0] + (size_t)(i * 256 + wv * 64) * 16);
    }
#pragma unroll
    for (int i = 0; i < 4; i++) {          // V: [row d 0..127][col s], 128B rows
      const int c    = i * 256 + tid;
      const int row  = c >> 3;
      const int colb = (c & 7) << 4;
      const int scol = (colb ^ ((row & 7) << 4)) >> 1;
      gload_lds16(Vh + (size_t)row * T_LEN + s0 + scol,
                  (char*)&Vs[b][0] + (size_t)(i * 256 + wv * 64) * 16);
    }
  };

  int cur = 0;
  STAGE(0, 0);
  __syncthreads();   // implicit vmcnt(0) drain -> tile 0 ready

  for (int t = 0; t < nt; ++t) {
    if (t + 1 < nt) STAGE(cur ^ 1, t + 1);   // prefetch next tile
    const int s0 = t * 64;
    const char* KsB = (const char*)&Ks[cur][0];
    const char* VsB = (const char*)&Vs[cur][0];

    // ---- scores: each K fragment feeds both row-groups
    float scv[2][4][4];
#pragma unroll
    for (int sub = 0; sub < 4; sub++) {
      const char* Kbase = KsB + (sub * 16 + fr) * 256;
      f32x4 a0 = zero, a1 = zero;
#pragma unroll
      for (int d0 = 0; d0 < 4; d0++) {
        short8v kf = *(const short8v*)(Kbase + ((d0 * 64 + fkb) ^ swz));
        a0 = __builtin_amdgcn_mfma_f32_16x16x32_bf16(qf[0][d0], kf, a0, 0, 0, 0);
        a1 = __builtin_amdgcn_mfma_f32_16x16x32_bf16(qf[1][d0], kf, a1, 0, 0, 0);
      }
#pragma unroll
      for (int j = 0; j < 4; j++) {
        scv[0][sub][j] = a0[j] * scale;
        scv[1][sub][j] = a1[j] * scale;
      }
    }
    // ---- causal mask: provably only the last two tiles touch the diagonal
    if (t >= nt - 2) {
#pragma unroll
      for (int g = 0; g < 2; g++)
#pragma unroll
        for (int sub = 0; sub < 4; sub++) {
          const int colp = s0 + sub * 16 + fr;
#pragma unroll
          for (int j = 0; j < 4; j++)
            if (colp > qrow0 + g * 16 + rg + j) scv[g][sub][j] = -1e30f;
        }
    }
    // ---- defer-max gate (T13, THR=8)
    float pmax[2][4];
#pragma unroll
    for (int g = 0; g < 2; g++)
#pragma unroll
      for (int j = 0; j < 4; j++)
        pmax[g][j] = fmaxf(fmaxf(scv[g][0][j], scv[g][1][j]),
                           fmaxf(scv[g][2][j], scv[g][3][j]));
    float growth = -1e30f;
#pragma unroll
    for (int g = 0; g < 2; g++)
#pragma unroll
      for (int j = 0; j < 4; j++) growth = fmaxf(growth, pmax[g][j] - mrow[g][j]);
    if (!__all(growth <= 8.0f)) {
      // rare path: full row-max reduce + rescale (first iteration always here)
#pragma unroll
      for (int g = 0; g < 2; g++)
#pragma unroll
        for (int j = 0; j < 4; j++) {
          float mx = pmax[g][j];
#pragma unroll
          for (int d = 1; d < 16; d <<= 1) mx = fmaxf(mx, __shfl_xor(mx, d));
          const float mn = fmaxf(mrow[g][j], mx);
          const float c  = __expf(mrow[g][j] - mn);
          mrow[g][j] = mn;
          lrow[g][j] *= c;
#pragma unroll
          for (int df = 0; df < 8; df++) o[g][df][j] *= c;
        }
    }
    // ---- exp + per-lane l + P -> swizzled LDS (no cross-lane ops)
#pragma unroll
    for (int g = 0; g < 2; g++)
#pragma unroll
      for (int j = 0; j < 4; j++) {
        const int prow = g * 16 + rg + j;
        char* prb = pb + prow * 128;
        const int rswz = ((rg + j) & 7) << 4;
        float ps = 0.f;
#pragma unroll
        for (int sub = 0; sub < 4; sub++) {
          const float p = __expf(scv[g][sub][j] - mrow[g][j]);
          ps += p;
          *(short*)(prb + ((((sub * 16 + fr) << 1)) ^ rswz)) = f2bf(p);
        }
        lrow[g][j] += ps;
      }
    asm volatile("" ::: "memory");  // order LDS writes before A-frag reads
    // ---- PV: each V fragment feeds both row-groups
    short8v pf[2][2];
#pragma unroll
    for (int g = 0; g < 2; g++)
#pragma unroll
      for (int ks = 0; ks < 2; ks++)
        pf[g][ks] = *(const short8v*)(pb + (g * 16 + fr) * 128 + ((ks * 64 + fkb) ^ swz));
#pragma unroll
    for (int df = 0; df < 8; df++) {
      const char* Vbase = VsB + (df * 16 + fr) * 128;
      short8v vf0 = *(const short8v*)(Vbase + ((0 + fkb) ^ swz));
      short8v vf1 = *(const short8v*)(Vbase + ((64 + fkb) ^ swz));
      o[0][df] = __builtin_amdgcn_mfma_f32_16x16x32_bf16(pf[0][0], vf0, o[0][df], 0, 0, 0);
      o[0][df] = __builtin_amdgcn_mfma_f32_16x16x32_bf16(pf[0][1], vf1, o[0][df], 0, 0, 0);
      o[1][df] = __builtin_amdgcn_mfma_f32_16x16x32_bf16(pf[1][0], vf0, o[1][df], 0, 0, 0);
      o[1][df] = __builtin_amdgcn_mfma_f32_16x16x32_bf16(pf[1][1], vf1, o[1][df], 0, 0, 0);
    }
    __syncthreads();   // drains vmcnt (prefetch landed) + frees buffer cur
    cur ^= 1;
  }

  // ---- final denominator reduce + output
#pragma unroll
  for (int g = 0; g < 2; g++)
#pragma unroll
    for (int j = 0; j < 4; j++) {
#pragma unroll
      for (int d = 1; d < 16; d <<= 1) lrow[g][j] += __shfl_xor(lrow[g][j], d);
    }
#pragma unroll
  for (int g = 0; g < 2; g++)
#pragma unroll
    for (int df = 0; df < 8; df++)
#pragma unroll
      for (int j = 0; j < 4; j++) {
        const float v = o[g][df][j] / lrow[g][j];
        attn_out[(size_t)(qrow0 + g * 16 + rg + j) * HDIM + h * HEADD + df * 16 + fr] = f2bf(v);
      }
}

// ---------------- launch ----------------
extern "C" void kernel_launch(void* const* d_in, const int* in_sizes, int n_in,
                              void* d_out, int out_size, void* d_ws, size_t ws_size,
                              hipStream_t stream) {
  (void)out_size; (void)ws_size;
  // size-based input remap (robust to any d_in permutation; sizes are unique)
  int ip = 0, ih = 1, iwq = 2, ib = 3, iwd = 4, il0 = 5, il1 = 6;
  if (n_in == 7) {
    int p = -1, hh = -1, wq = -1, b = -1, wd = -1, l0 = -1, l1 = -1, ok = 1;
    for (int i = 0; i < 7; i++) {
      switch (in_sizes[i]) {
        case 2048:     p  = i; break;
        case 8388608:  hh = i; break;
        case 18874368: wq = i; break;
        case 4608:     b  = i; break;
        case 16777216: wd = i; break;
        case 128:      if (l0 < 0) l0 = i; else l1 = i; break;
        default:       ok = 0; break;
      }
    }
    if (ok && p >= 0 && hh >= 0 && wq >= 0 && b >= 0 && wd >= 0 && l0 >= 0 && l1 >= 0) {
      ip = p; ih = hh; iwq = wq; ib = b; iwd = wd; il0 = l0; il1 = l1;
    }
  }

  const int*   positions = (const int*)d_in[ip];
  const float* hidden    = (const float*)d_in[ih];
  const float* w_qkv     = (const float*)d_in[iwq];
  const float* b_qkv     = (const float*)d_in[ib];
  const float* w_dense   = (const float*)d_in[iwd];
  const float* q_ln      = (const float*)d_in[il0];
  const float* k_ln      = (const float*)d_in[il1];

  char* ws = (char*)d_ws;
  // lifetime-aliased workspace (peak ~92.3 MB):
  short* Ahs   = (short*)(ws + 0);                   // 16.8 MB (dead after gemm1)
  short* Qb    = (short*)(ws + 0);                   // 16.8 MB (aliases Ahs)
  short* Wqkv  = (short*)(ws + (size_t)16777216);    // 37.7 MB (dead after gemm1)
  short* Kb    = (short*)(ws + (size_t)16777216);    // 1.0 MB  (aliases Wqkv)
  short* Vt    = (short*)(ws + (size_t)17825792);    // 1.0 MB  (aliases Wqkv)
  short* Wd    = (short*)(ws + (size_t)18874368);    // 33.5 MB (aliases Wqkv)
  float* qkvf  = (float*)(ws + (size_t)54525952);    // 37.7 MB f32 (dead after qkv_post)
  short* attnb = (short*)(ws + (size_t)54525952);    // 16.8 MB (aliases qkvf)

  cast_f32_to_bf16<<<dim3(1024), dim3(256), 0, stream>>>(hidden, Ahs, (T_LEN * HDIM) / 4);
  cast_f32_to_bf16<<<dim3(2048), dim3(256), 0, stream>>>(w_qkv, Wqkv, (QKVN * HDIM) / 4);
  gemm_bt<<<dim3(QKVN / 128, T_LEN / 128), dim3(256), 0, stream>>>(
      Ahs, Wqkv, b_qkv, qkvf, T_LEN, QKVN, HDIM);
  qkv_post_kernel<<<dim3(T_LEN, 36), dim3(64), 0, stream>>>(
      qkvf, positions, q_ln, k_ln, Qb, Kb, Vt);
  cast_f32_to_bf16<<<dim3(2048), dim3(256), 0, stream>>>(w_dense, Wd, (HDIM * HDIM) / 4);
  attn_kernel<<<dim3(16, NHEADS), dim3(256), 0, stream>>>(Qb, Kb, Vt, attnb);
  gemm_bt<<<dim3(HDIM / 128, T_LEN / 128), dim3(256), 0, stream>>>(
      attnb, Wd, nullptr, (float*)d_out, T_LEN, HDIM, HDIM);
}